// Round 1
// baseline (1630.585 us; speedup 1.0000x reference)
//
#include <hip/hip_runtime.h>
#include <math.h>

#define NN 128
#define HH 128
#define LL 4097
#define PH 2049   // half points = L/2 + 1
#define BP 64     // points per block tile
#define NTILE 33  // ceil(2049/64)

// Big layer: out[i] = relu(W @ in_h + b), dout[i] = relu'(pre) * (W @ in_dh)
// LDS layout: buf[j*128 + p] = h, buf[j*128 + 64 + p] = dh, p in [0,64)
__device__ __forceinline__ void big_layer(
    const float* __restrict__ wn, const float* __restrict__ bn,
    const float* in_lds, float* out_lds, int i0, int p)
{
    float acc[16], dacc[16];
#pragma unroll
    for (int k = 0; k < 16; ++k) { acc[k] = bn[i0 + k]; dacc[k] = 0.f; }
#pragma unroll 8
    for (int j = 0; j < HH; ++j) {
        const float h  = in_lds[j * 128 + p];
        const float dh = in_lds[j * 128 + 64 + p];
#pragma unroll
        for (int k = 0; k < 16; ++k) {
            const float wv = wn[(i0 + k) * HH + j];
            acc[k]  = fmaf(wv, h,  acc[k]);
            dacc[k] = fmaf(wv, dh, dacc[k]);
        }
    }
#pragma unroll
    for (int k = 0; k < 16; ++k) {
        const float pre = acc[k];
        const bool  on  = pre > 0.f;
        out_lds[(i0 + k) * 128 + p]      = on ? pre     : 0.f;
        out_lds[(i0 + k) * 128 + 64 + p] = on ? dacc[k] : 0.f;
    }
}

__global__ __launch_bounds__(512, 1) void sofa_kernel(
    const float* __restrict__ alpha,
    const float* __restrict__ w0, const float* __restrict__ w1,
    const float* __restrict__ w2, const float* __restrict__ w3,
    const float* __restrict__ b0, const float* __restrict__ b1,
    const float* __restrict__ b2, const float* __restrict__ b3,
    const float* __restrict__ sqrt_a,
    float* __restrict__ out)
{
    __shared__ float A[HH * 2 * BP];  // 64 KB
    __shared__ float B[HH * 2 * BP];  // 64 KB

    const int tile = blockIdx.x;
    const int n    = blockIdx.y;
    const int tid  = threadIdx.x;
    const int p    = tid & 63;
    const int g    = __builtin_amdgcn_readfirstlane(tid >> 6); // wave id, 0..7

    const int   pg = tile * BP + p;
    const float a  = alpha[pg < PH ? pg : 0];

    // ---- layer 0: scalar input, tangent(alpha) = 1 ----
    {
        const float* w0n = w0 + n * HH;
        const float* b0n = b0 + n * HH;
#pragma unroll
        for (int m = 0; m < 16; ++m) {
            const int   j   = g * 16 + m;
            const float w   = w0n[j];
            const float pre = fmaf(w, a, b0n[j]);
            const bool  on  = pre > 0.f;
            A[j * 128 + p]      = on ? pre : 0.f;
            A[j * 128 + 64 + p] = on ? w   : 0.f;
        }
    }
    __syncthreads();

    const int i0 = g * 16;

    // ---- layer 1: A -> B ----
    big_layer(w1 + n * HH * HH, b1 + n * HH, A, B, i0, p);
    __syncthreads();

    // ---- layer 2: B -> A ----
    big_layer(w2 + n * HH * HH, b2 + n * HH, B, A, i0, p);
    __syncthreads();

    // ---- layer 3 partials: each wave sums its 16 j's ----
    {
        const float* w3n = w3 + n * HH;
        float o = 0.f, dd = 0.f;
#pragma unroll
        for (int m = 0; m < 16; ++m) {
            const int   j = i0 + m;
            const float w = w3n[j];
            o  = fmaf(w, A[j * 128 + p],      o);
            dd = fmaf(w, A[j * 128 + 64 + p], dd);
        }
        B[g * 128 + p]      = o;
        B[g * 128 + 64 + p] = dd;
    }
    __syncthreads();

    // ---- reduce + square + JVP + trig epilogue (64 threads) ----
    if (tid < 64) {
        float oo = b3[n];   // (N,1) bias
        float d2 = 0.f;
#pragma unroll
        for (int q = 0; q < 8; ++q) {
            oo += B[q * 128 + tid];
            d2 += B[q * 128 + 64 + tid];
        }
        const float bb = oo * oo;          // b = out^2
        const float db = 2.f * oo * d2;    // db = 2*out*dout
        const float sa = sqrt_a[n];
        const float af = sa * sa;
        const int   NL = NN * LL;
        const int   k1 = tile * BP + tid;
        if (k1 < PH) {
            {
                const float al = alpha[k1];
                const float sn = sinf(al), cs = cosf(al);
                const int base = n * LL + k1;
                out[base]          = af * (cs - 1.f);
                out[NL + base]     = bb * sn;
                out[2 * NL + base] = -af * sn;
                out[3 * NL + base] = fmaf(bb, cs, db * sn);
            }
            // mirror half: k2 in [2049, 4096] from k1 in [0, 2047]
            if (k1 <= PH - 2) {
                const int   k2  = (LL - 1) - k1;
                const float al2 = alpha[k2];
                const float sn2 = sinf(al2), cs2 = cosf(al2);
                const int base2 = n * LL + k2;
                out[base2]          = af * (cs2 - 1.f);
                out[NL + base2]     = bb * sn2;
                out[2 * NL + base2] = -af * sn2;
                out[3 * NL + base2] = fmaf(bb, cs2, -db * sn2);
            }
        }
    }
}

extern "C" void kernel_launch(void* const* d_in, const int* in_sizes, int n_in,
                              void* d_out, int out_size, void* d_ws, size_t ws_size,
                              hipStream_t stream) {
    const float* alpha  = (const float*)d_in[0];
    const float* w0     = (const float*)d_in[1];
    const float* w1     = (const float*)d_in[2];
    const float* w2     = (const float*)d_in[3];
    const float* w3     = (const float*)d_in[4];
    const float* b0     = (const float*)d_in[5];
    const float* b1     = (const float*)d_in[6];
    const float* b2     = (const float*)d_in[7];
    const float* b3     = (const float*)d_in[8];
    const float* sqrt_a = (const float*)d_in[9];
    (void)in_sizes; (void)n_in; (void)out_size; (void)d_ws; (void)ws_size;

    dim3 grid(NTILE, NN);
    sofa_kernel<<<grid, 512, 0, stream>>>(alpha, w0, w1, w2, w3,
                                          b0, b1, b2, b3, sqrt_a,
                                          (float*)d_out);
}

// Round 2
// 1191.941 us; speedup vs baseline: 1.3680x; 1.3680x over previous
//
#include <hip/hip_runtime.h>
#include <math.h>

#define NN 128
#define HH 128
#define LL 4097
#define PH 2049   // half points = L/2 + 1
#define BP 64     // points per block tile
#define NTILE 33  // ceil(2049/64)

// In-place big layer: read ALL of buf into 32 accumulators, barrier,
// write relu(pre)/relu'(pre)*dacc back into the SAME buffer.
// LDS layout: buf[j*128 + p] = h, buf[j*128 + 64 + p] = dh, p in [0,64)
__device__ __forceinline__ void big_layer_inplace(
    const float* __restrict__ wn, const float* __restrict__ bn,
    float* buf, int i0, int p)
{
    float acc[16], dacc[16];
#pragma unroll
    for (int k = 0; k < 16; ++k) { acc[k] = bn[i0 + k]; dacc[k] = 0.f; }
#pragma unroll 8
    for (int j = 0; j < HH; ++j) {
        const float h  = buf[j * 128 + p];
        const float dh = buf[j * 128 + 64 + p];
#pragma unroll
        for (int k = 0; k < 16; ++k) {
            const float wv = wn[(i0 + k) * HH + j];
            acc[k]  = fmaf(wv, h,  acc[k]);
            dacc[k] = fmaf(wv, dh, dacc[k]);
        }
    }
    __syncthreads();   // everyone done READING buf
#pragma unroll
    for (int k = 0; k < 16; ++k) {
        const float pre = acc[k];
        const bool  on  = pre > 0.f;
        buf[(i0 + k) * 128 + p]      = on ? pre     : 0.f;
        buf[(i0 + k) * 128 + 64 + p] = on ? dacc[k] : 0.f;
    }
    __syncthreads();   // buf now holds this layer's output
}

__global__ __launch_bounds__(512, 4) void sofa_kernel(
    const float* __restrict__ alpha,
    const float* __restrict__ w0, const float* __restrict__ w1,
    const float* __restrict__ w2, const float* __restrict__ w3,
    const float* __restrict__ b0, const float* __restrict__ b1,
    const float* __restrict__ b2, const float* __restrict__ b3,
    const float* __restrict__ sqrt_a,
    float* __restrict__ out)
{
    __shared__ float A[HH * 2 * BP];  // 64 KB single buffer -> 2 blocks/CU

    const int tile = blockIdx.x;
    const int n    = blockIdx.y;
    const int tid  = threadIdx.x;
    const int p    = tid & 63;
    const int g    = __builtin_amdgcn_readfirstlane(tid >> 6); // wave id, 0..7

    const int   pg = tile * BP + p;
    const float a  = alpha[pg < PH ? pg : 0];

    // ---- layer 0: scalar input, tangent(alpha) = 1 ----
    {
        const float* w0n = w0 + n * HH;
        const float* b0n = b0 + n * HH;
#pragma unroll
        for (int m = 0; m < 16; ++m) {
            const int   j   = g * 16 + m;
            const float w   = w0n[j];
            const float pre = fmaf(w, a, b0n[j]);
            const bool  on  = pre > 0.f;
            A[j * 128 + p]      = on ? pre : 0.f;
            A[j * 128 + 64 + p] = on ? w   : 0.f;
        }
    }
    __syncthreads();

    const int i0 = g * 16;

    // ---- layer 1 (in place) ----
    big_layer_inplace(w1 + n * HH * HH, b1 + n * HH, A, i0, p);

    // ---- layer 2 (in place) ----
    big_layer_inplace(w2 + n * HH * HH, b2 + n * HH, A, i0, p);

    // ---- layer 3 partials: each wave sums its 16 j's ----
    {
        const float* w3n = w3 + n * HH;
        float o = 0.f, dd = 0.f;
#pragma unroll
        for (int m = 0; m < 16; ++m) {
            const int   j = i0 + m;
            const float w = w3n[j];
            o  = fmaf(w, A[j * 128 + p],      o);
            dd = fmaf(w, A[j * 128 + 64 + p], dd);
        }
        __syncthreads();   // done reading A
        A[g * 128 + p]      = o;
        A[g * 128 + 64 + p] = dd;
    }
    __syncthreads();

    // ---- reduce + square + JVP + trig epilogue (64 threads) ----
    if (tid < 64) {
        float oo = b3[n];   // (N,1) bias
        float d2 = 0.f;
#pragma unroll
        for (int q = 0; q < 8; ++q) {
            oo += A[q * 128 + tid];
            d2 += A[q * 128 + 64 + tid];
        }
        const float bb = oo * oo;          // b = out^2
        const float db = 2.f * oo * d2;    // db = 2*out*dout
        const float sa = sqrt_a[n];
        const float af = sa * sa;
        const int   NL = NN * LL;
        const int   k1 = tile * BP + tid;
        if (k1 < PH) {
            {
                const float al = alpha[k1];
                const float sn = sinf(al), cs = cosf(al);
                const int base = n * LL + k1;
                out[base]          = af * (cs - 1.f);
                out[NL + base]     = bb * sn;
                out[2 * NL + base] = -af * sn;
                out[3 * NL + base] = fmaf(bb, cs, db * sn);
            }
            // mirror half: k2 in [2049, 4096] from k1 in [0, 2047]
            if (k1 <= PH - 2) {
                const int   k2  = (LL - 1) - k1;
                const float al2 = alpha[k2];
                const float sn2 = sinf(al2), cs2 = cosf(al2);
                const int base2 = n * LL + k2;
                out[base2]          = af * (cs2 - 1.f);
                out[NL + base2]     = bb * sn2;
                out[2 * NL + base2] = -af * sn2;
                out[3 * NL + base2] = fmaf(bb, cs2, -db * sn2);
            }
        }
    }
}

extern "C" void kernel_launch(void* const* d_in, const int* in_sizes, int n_in,
                              void* d_out, int out_size, void* d_ws, size_t ws_size,
                              hipStream_t stream) {
    const float* alpha  = (const float*)d_in[0];
    const float* w0     = (const float*)d_in[1];
    const float* w1     = (const float*)d_in[2];
    const float* w2     = (const float*)d_in[3];
    const float* w3     = (const float*)d_in[4];
    const float* b0     = (const float*)d_in[5];
    const float* b1     = (const float*)d_in[6];
    const float* b2     = (const float*)d_in[7];
    const float* b3     = (const float*)d_in[8];
    const float* sqrt_a = (const float*)d_in[9];
    (void)in_sizes; (void)n_in; (void)out_size; (void)d_ws; (void)ws_size;

    dim3 grid(NTILE, NN);
    sofa_kernel<<<grid, 512, 0, stream>>>(alpha, w0, w1, w2, w3,
                                          b0, b1, b2, b3, sqrt_a,
                                          (float*)d_out);
}

// Round 4
// 262.410 us; speedup vs baseline: 6.2139x; 4.5423x over previous
//
#include <hip/hip_runtime.h>
#include <math.h>

#define NN 128
#define HH 128
#define LL 4097
#define PH 2049
#define BP 64     // points per block
#define NTILE 33  // ceil(2049/64)

typedef short bf16x8 __attribute__((ext_vector_type(8)));
typedef float f32x4  __attribute__((ext_vector_type(4)));
typedef unsigned int u32;

// split f32 -> hi (bf16 by truncation) + lo (bf16 round-half-up of residual)
__device__ __forceinline__ void split1(float x, u32& hi, u32& lo) {
    u32 bx = __float_as_uint(x);
    hi = bx >> 16;
    float hf = __uint_as_float(bx & 0xffff0000u);
    float d  = x - hf;
    lo = (__float_as_uint(d) + 0x8000u) >> 16;
}

__device__ __forceinline__ f32x4 MF(bf16x8 a, bf16x8 b, f32x4 c) {
    return __builtin_amdgcn_mfma_f32_16x16x32_bf16(a, b, c, 0, 0, 0);
}

// Frag layout (both W and X buffers): frag fq = tile16*4 + kstep (tile16: 8 row/col
// tiles of 16; kstep: 4 steps of K=32), then hi/lo: slot = (fq*2+hl)*64 + lane,
// 16 bytes per slot. Lane l holds: row/col = l&15, k = kstep*32 + (l>>4)*8 + e.
// W buffer 64 KB at smem[0], X buffer 64 KB at smem[65536].

// stage one 128x128 fp32 weight matrix -> frag-linear hi/lo bf16 in LDS
__device__ __forceinline__ void stageW(const float* __restrict__ wn, char* Wb, int tid) {
#pragma unroll
    for (int it = 0; it < 4; ++it) {
        const int s  = tid + it * 512;
        const int l  = s & 63;
        const int fq = s >> 6;          // 0..31 : it7 = fq>>2, ks = fq&3
        const int ks = fq & 3, it7 = fq >> 2;
        const int i  = it7 * 16 + (l & 15);
        const int k0 = ks * 32 + (l >> 4) * 8;
        const float4* src = (const float4*)(wn + i * HH + k0);
        const float4 va = src[0], vb = src[1];
        const float v[8] = {va.x, va.y, va.z, va.w, vb.x, vb.y, vb.z, vb.w};
        u32 hd[4], ld_[4];
#pragma unroll
        for (int q = 0; q < 4; ++q) {
            u32 h0, l0, h1, l1;
            split1(v[2*q], h0, l0); split1(v[2*q+1], h1, l1);
            hd[q]  = h0 | (h1 << 16);
            ld_[q] = l0 | (l1 << 16);
        }
        *(uint4*)(Wb + (((fq*2)+0)*64 + l)*16) = make_uint4(hd[0], hd[1], hd[2], hd[3]);
        *(uint4*)(Wb + (((fq*2)+1)*64 + l)*16) = make_uint4(ld_[0], ld_[1], ld_[2], ld_[3]);
    }
}

// one 128x128x128 GEMM from frag-linear LDS; wave (rw,cw): rows rw*64..+64,
// cols {cw*16..+16 (h), 64+cw*16..+16 (dh)}; acc[itl][cg] cg0=h cg1=dh
__device__ __forceinline__ void gemm128(const char* Wb, const char* Xb,
                                        f32x4 acc[4][2], int rw, int cw, int l) {
    const bf16x8* Wf = (const bf16x8*)Wb;
    const bf16x8* Xf = (const bf16x8*)Xb;
#pragma unroll
    for (int ks = 0; ks < 4; ++ks) {
        bf16x8 Bh[2], Bl[2];
#pragma unroll
        for (int cg = 0; cg < 2; ++cg) {
            const int ct = cw + cg * 4;
            Bh[cg] = Xf[((ct*4 + ks)*2 + 0)*64 + l];
            Bl[cg] = Xf[((ct*4 + ks)*2 + 1)*64 + l];
        }
#pragma unroll
        for (int itl = 0; itl < 4; ++itl) {
            const int IT = rw * 4 + itl;
            const bf16x8 Ah = Wf[((IT*4 + ks)*2 + 0)*64 + l];
            const bf16x8 Al = Wf[((IT*4 + ks)*2 + 1)*64 + l];
#pragma unroll
            for (int cg = 0; cg < 2; ++cg) {
                acc[itl][cg] = MF(Ah, Bh[cg], acc[itl][cg]);
                acc[itl][cg] = MF(Ah, Bl[cg], acc[itl][cg]);
                acc[itl][cg] = MF(Al, Bh[cg], acc[itl][cg]);
            }
        }
    }
}

__global__ __launch_bounds__(512, 2) void sofa_mfma(
    const float* __restrict__ alpha,
    const float* __restrict__ w0, const float* __restrict__ w1,
    const float* __restrict__ w2, const float* __restrict__ w3,
    const float* __restrict__ b0, const float* __restrict__ b1,
    const float* __restrict__ b2, const float* __restrict__ b3,
    const float* __restrict__ sqrt_a,
    float* __restrict__ out)
{
    __shared__ char smem[131072];
    char* Wb = smem;
    char* Xb = smem + 65536;
    float* red = (float*)smem;   // reused after GEMM2: [0:64)=H rw0, [64:128)=H rw1,
                                 // [128:192)=D rw0, [192:256)=D rw1

    const int tile = blockIdx.x, n = blockIdx.y;
    const int tid = threadIdx.x;
    const int l   = tid & 63;
    const int w   = tid >> 6;
    const int rw  = w & 1;       // row half (64 rows)
    const int cw  = w >> 1;      // col quarter, 0..3
    const int t   = l >> 4;

    // ---- stage W1 ----
    stageW(w1 + n * HH * HH, Wb, tid);

    // ---- layer 0: elementwise, write X1 frags ----
    {
        const float* w0n = w0 + n * HH;
        const float* b0n = b0 + n * HH;
        const int c  = tid & 127;        // col: <64 h(point c), >=64 dh(point c-64)
        const int jb = tid >> 7;         // kstep 0..3
        int p = tile * BP + (c & 63);
        if (p > 2048) p = 2048;
        const float a = alpha[p];
        const bool isdh = c >= 64;
        const int ct = c >> 4;
#pragma unroll
        for (int g8 = 0; g8 < 4; ++g8) {
            u32 hd[4], ld_[4];
#pragma unroll
            for (int q = 0; q < 4; ++q) {
                float vv[2];
#pragma unroll
                for (int e = 0; e < 2; ++e) {
                    const int j = jb * 32 + g8 * 8 + q * 2 + e;
                    const float wv  = w0n[j];
                    const float pre = fmaf(wv, a, b0n[j]);
                    const bool  on  = pre > 0.f;
                    vv[e] = isdh ? (on ? wv : 0.f) : (on ? pre : 0.f);
                }
                u32 h0, l0, h1, l1;
                split1(vv[0], h0, l0); split1(vv[1], h1, l1);
                hd[q]  = h0 | (h1 << 16);
                ld_[q] = l0 | (l1 << 16);
            }
            const int lane = g8 * 16 + (c & 15);
            const int fq   = ct * 4 + jb;
            *(uint4*)(Xb + ((fq*2 + 0)*64 + lane)*16) = make_uint4(hd[0], hd[1], hd[2], hd[3]);
            *(uint4*)(Xb + ((fq*2 + 1)*64 + lane)*16) = make_uint4(ld_[0], ld_[1], ld_[2], ld_[3]);
        }
    }
    __syncthreads();

    // ---- GEMM 1 ----
    f32x4 acc[4][2];
#pragma unroll
    for (int i0 = 0; i0 < 4; ++i0)
#pragma unroll
        for (int c0 = 0; c0 < 2; ++c0) { f32x4 z = {0.f,0.f,0.f,0.f}; acc[i0][c0] = z; }
    gemm128(Wb, Xb, acc, rw, cw, l);

    // ---- transition: bias + relu + split/pack X2 in regs ----
    u32 px[4][2][2][2];  // [itl][cg][hl][dword]
    {
        const float* b1n = b1 + n * HH;
#pragma unroll
        for (int itl = 0; itl < 4; ++itl) {
            const int ibase = (rw*4 + itl)*16 + t*4;
            float hv[4], dv[4];
#pragma unroll
            for (int r = 0; r < 4; ++r) {
                const float pre = acc[itl][0][r] + b1n[ibase + r];
                const bool  on  = pre > 0.f;
                hv[r] = on ? pre : 0.f;
                dv[r] = on ? acc[itl][1][r] : 0.f;
            }
#pragma unroll
            for (int cg = 0; cg < 2; ++cg) {
                const float* vs = cg ? dv : hv;
                u32 a0,c0,a1,c1,a2,c2,a3,c3;
                split1(vs[0],a0,c0); split1(vs[1],a1,c1);
                split1(vs[2],a2,c2); split1(vs[3],a3,c3);
                px[itl][cg][0][0] = a0 | (a1 << 16);
                px[itl][cg][0][1] = a2 | (a3 << 16);
                px[itl][cg][1][0] = c0 | (c1 << 16);
                px[itl][cg][1][1] = c2 | (c3 << 16);
            }
        }
    }
    __syncthreads();   // all GEMM1 reads of W1/X1 complete

    // ---- stage W2 + write X2 frags ----
    stageW(w2 + n * HH * HH, Wb, tid);
    {
#pragma unroll
        for (int itl = 0; itl < 4; ++itl) {
            const int IT   = rw*4 + itl;
            const int lane = ((IT & 1)*2 + (t >> 1))*16 + (l & 15);
            const int off8 = (t & 1)*8;
            const int ksn  = IT >> 1;
#pragma unroll
            for (int cg = 0; cg < 2; ++cg) {
                const int fq = (cw + cg*4)*4 + ksn;
#pragma unroll
                for (int hl = 0; hl < 2; ++hl) {
                    uint2 vv; vv.x = px[itl][cg][hl][0]; vv.y = px[itl][cg][hl][1];
                    *(uint2*)(Xb + ((fq*2 + hl)*64 + lane)*16 + off8) = vv;
                }
            }
        }
    }
    __syncthreads();

    // ---- GEMM 2 ----
    f32x4 acc2[4][2];
#pragma unroll
    for (int i0 = 0; i0 < 4; ++i0)
#pragma unroll
        for (int c0 = 0; c0 < 2; ++c0) { f32x4 z = {0.f,0.f,0.f,0.f}; acc2[i0][c0] = z; }
    gemm128(Wb, Xb, acc2, rw, cw, l);

    // ---- layer 3: bias+relu then reduce with w3 ----
    float sh = 0.f, sd = 0.f;
    {
        const float* b2n = b2 + n * HH;
        const float* w3n = w3 + n * HH;
#pragma unroll
        for (int itl = 0; itl < 4; ++itl) {
            const int ibase = (rw*4 + itl)*16 + t*4;
#pragma unroll
            for (int r = 0; r < 4; ++r) {
                const int   i   = ibase + r;
                const float pre = acc2[itl][0][r] + b2n[i];
                const bool  on  = pre > 0.f;
                const float hv  = on ? pre : 0.f;
                const float dv  = on ? acc2[itl][1][r] : 0.f;
                const float wv  = w3n[i];
                sh = fmaf(wv, hv, sh);
                sd = fmaf(wv, dv, sd);
            }
        }
    }
    sh += __shfl_xor(sh, 16); sh += __shfl_xor(sh, 32);
    sd += __shfl_xor(sd, 16); sd += __shfl_xor(sd, 32);
    __syncthreads();   // done reading W LDS -> reuse as reduction buffer
    if (t == 0) {
        const int p = cw * 16 + (l & 15);
        red[rw * 64 + p]        = sh;
        red[128 + rw * 64 + p]  = sd;
    }
    __syncthreads();

    // ---- epilogue (64 threads): square + JVP + trig, write both halves ----
    if (tid < 64) {
        const float oo = b3[n] + red[tid] + red[64 + tid];
        const float d2 = red[128 + tid] + red[192 + tid];
        const float bb = oo * oo;
        const float db = 2.f * oo * d2;
        const float sa = sqrt_a[n];
        const float af = sa * sa;
        const int   NL = NN * LL;
        const int   k1 = tile * BP + tid;
        if (k1 < PH) {
            {
                const float al = alpha[k1];
                const float sn = sinf(al), cs = cosf(al);
                const int base = n * LL + k1;
                out[base]          = af * (cs - 1.f);
                out[NL + base]     = bb * sn;
                out[2 * NL + base] = -af * sn;
                out[3 * NL + base] = fmaf(bb, cs, db * sn);
            }
            if (k1 <= PH - 2) {
                const int   k2  = (LL - 1) - k1;
                const float al2 = alpha[k2];
                const float sn2 = sinf(al2), cs2 = cosf(al2);
                const int base2 = n * LL + k2;
                out[base2]          = af * (cs2 - 1.f);
                out[NL + base2]     = bb * sn2;
                out[2 * NL + base2] = -af * sn2;
                out[3 * NL + base2] = fmaf(bb, cs2, -db * sn2);
            }
        }
    }
}

extern "C" void kernel_launch(void* const* d_in, const int* in_sizes, int n_in,
                              void* d_out, int out_size, void* d_ws, size_t ws_size,
                              hipStream_t stream) {
    const float* alpha  = (const float*)d_in[0];
    const float* w0     = (const float*)d_in[1];
    const float* w1     = (const float*)d_in[2];
    const float* w2     = (const float*)d_in[3];
    const float* w3     = (const float*)d_in[4];
    const float* b0     = (const float*)d_in[5];
    const float* b1     = (const float*)d_in[6];
    const float* b2     = (const float*)d_in[7];
    const float* b3     = (const float*)d_in[8];
    const float* sqrt_a = (const float*)d_in[9];
    (void)in_sizes; (void)n_in; (void)out_size; (void)d_ws; (void)ws_size;

    dim3 grid(NTILE, NN);
    sofa_mfma<<<grid, 512, 0, stream>>>(alpha, w0, w1, w2, w3,
                                        b0, b1, b2, b3, sqrt_a,
                                        (float*)d_out);
}

// Round 5
// 215.471 us; speedup vs baseline: 7.5676x; 1.2178x over previous
//
#include <hip/hip_runtime.h>
#include <math.h>

#define NN 128
#define HH 128
#define LL 4097
#define PH 2049
#define BP 64     // points per block
#define NTILE 33  // ceil(2049/64)
// pre-split weight frags: 2 mats * 128 nets * 64 slots * 64 lanes * 16 B
#define WS_NEEDED (2u * 128u * 64u * 64u * 16u)

typedef short bf16x8 __attribute__((ext_vector_type(8)));
typedef float f32x4  __attribute__((ext_vector_type(4)));
typedef unsigned int u32;

// split f32 -> hi (bf16 by truncation) + lo (bf16 round-half-up of residual)
__device__ __forceinline__ void split1(float x, u32& hi, u32& lo) {
    u32 bx = __float_as_uint(x);
    hi = bx >> 16;
    float hf = __uint_as_float(bx & 0xffff0000u);
    float d  = x - hf;
    lo = (__float_as_uint(d) + 0x8000u) >> 16;
}

__device__ __forceinline__ f32x4 MF(bf16x8 a, bf16x8 b, f32x4 c) {
    return __builtin_amdgcn_mfma_f32_16x16x32_bf16(a, b, c, 0, 0, 0);
}

// Frag layout (W in global d_ws, X in LDS): frag fq = tile16*4 + kstep, hi/lo:
// slot = fq*2+hl; 16 B per lane at slot*1024 + lane*16.
// Lane l holds row/col = l&15, k = kstep*32 + (l>>4)*8 + e.

// ---------------- pre-pass: split w1,w2 into frag-linear hi/lo in d_ws --------
__global__ __launch_bounds__(512) void presplit(
    const float* __restrict__ w1, const float* __restrict__ w2, uint4* __restrict__ ws)
{
    const int b = blockIdx.x;            // 0..255 : m*128 + n
    const int m = b >> 7, n = b & 127;
    const float* wn = (m ? w2 : w1) + n * HH * HH;
    uint4* dst = ws + b * 4096;          // 64 slots * 64 lanes
    const int tid = threadIdx.x;
#pragma unroll
    for (int it = 0; it < 4; ++it) {
        const int s  = tid + it * 512;
        const int l  = s & 63;
        const int fq = s >> 6;           // rowtile*4 + ks
        const int ks = fq & 3, it7 = fq >> 2;
        const int i  = it7 * 16 + (l & 15);
        const int k0 = ks * 32 + (l >> 4) * 8;
        const float4* src = (const float4*)(wn + i * HH + k0);
        const float4 va = src[0], vb = src[1];
        const float v[8] = {va.x, va.y, va.z, va.w, vb.x, vb.y, vb.z, vb.w};
        u32 hd[4], ld_[4];
#pragma unroll
        for (int q = 0; q < 4; ++q) {
            u32 h0, l0, h1, l1;
            split1(v[2*q], h0, l0); split1(v[2*q+1], h1, l1);
            hd[q]  = h0 | (h1 << 16);
            ld_[q] = l0 | (l1 << 16);
        }
        dst[(fq*2 + 0)*64 + l] = make_uint4(hd[0], hd[1], hd[2], hd[3]);
        dst[(fq*2 + 1)*64 + l] = make_uint4(ld_[0], ld_[1], ld_[2], ld_[3]);
    }
}

// one 128x128x128 GEMM: A(W) frags straight from global to regs, B(X) from LDS
__device__ __forceinline__ void gemm_regW(const bf16x8* __restrict__ Wf, const char* Xb,
                                          f32x4 acc[4][2], int rw, int cw, int l) {
    const bf16x8* Xf = (const bf16x8*)Xb;
#pragma unroll
    for (int ks = 0; ks < 4; ++ks) {
        bf16x8 Bh[2], Bl[2];
#pragma unroll
        for (int cg = 0; cg < 2; ++cg) {
            const int ct = cw + cg * 4;
            Bh[cg] = Xf[((ct*4 + ks)*2 + 0)*64 + l];
            Bl[cg] = Xf[((ct*4 + ks)*2 + 1)*64 + l];
        }
#pragma unroll
        for (int itl = 0; itl < 4; ++itl) {
            const int IT = rw * 4 + itl;
            const bf16x8 Ah = Wf[((IT*4 + ks)*2 + 0)*64 + l];
            const bf16x8 Al = Wf[((IT*4 + ks)*2 + 1)*64 + l];
#pragma unroll
            for (int cg = 0; cg < 2; ++cg) {
                acc[itl][cg] = MF(Ah, Bh[cg], acc[itl][cg]);
                acc[itl][cg] = MF(Ah, Bl[cg], acc[itl][cg]);
                acc[itl][cg] = MF(Al, Bh[cg], acc[itl][cg]);
            }
        }
    }
}

__global__ __launch_bounds__(512, 4) void sofa_mfma2(
    const float* __restrict__ alpha,
    const float* __restrict__ w0, const float* __restrict__ w3,
    const float* __restrict__ b0, const float* __restrict__ b1,
    const float* __restrict__ b2, const float* __restrict__ b3,
    const float* __restrict__ sqrt_a,
    const uint4* __restrict__ ws,
    float* __restrict__ out)
{
    __shared__ char smem[65536];   // X frags only
    char*  Xb  = smem;
    float* red = (float*)smem;     // reused after GEMM2

    const int tile = blockIdx.x, n = blockIdx.y;
    const int tid = threadIdx.x;
    const int l   = tid & 63;
    const int w   = tid >> 6;
    const int rw  = w & 1;       // row half (64 rows)
    const int cw  = w >> 1;      // col quarter, 0..3
    const int t   = l >> 4;

    const bf16x8* W1f = (const bf16x8*)(ws + n * 4096);
    const bf16x8* W2f = (const bf16x8*)(ws + (128 + n) * 4096);

    // ---- layer 0: elementwise, write X1 frags ----
    {
        const float* w0n = w0 + n * HH;
        const float* b0n = b0 + n * HH;
        const int c  = tid & 127;        // col: <64 h(point c), >=64 dh(point c-64)
        const int jb = tid >> 7;         // kstep 0..3
        int p = tile * BP + (c & 63);
        if (p > 2048) p = 2048;
        const float a = alpha[p];
        const bool isdh = c >= 64;
        const int ct = c >> 4;
#pragma unroll
        for (int g8 = 0; g8 < 4; ++g8) {
            u32 hd[4], ld_[4];
#pragma unroll
            for (int q = 0; q < 4; ++q) {
                float vv[2];
#pragma unroll
                for (int e = 0; e < 2; ++e) {
                    const int j = jb * 32 + g8 * 8 + q * 2 + e;
                    const float wv  = w0n[j];
                    const float pre = fmaf(wv, a, b0n[j]);
                    const bool  on  = pre > 0.f;
                    vv[e] = isdh ? (on ? wv : 0.f) : (on ? pre : 0.f);
                }
                u32 h0, l0, h1, l1;
                split1(vv[0], h0, l0); split1(vv[1], h1, l1);
                hd[q]  = h0 | (h1 << 16);
                ld_[q] = l0 | (l1 << 16);
            }
            const int lane = g8 * 16 + (c & 15);
            const int fq   = ct * 4 + jb;
            *(uint4*)(Xb + ((fq*2 + 0)*64 + lane)*16) = make_uint4(hd[0], hd[1], hd[2], hd[3]);
            *(uint4*)(Xb + ((fq*2 + 1)*64 + lane)*16) = make_uint4(ld_[0], ld_[1], ld_[2], ld_[3]);
        }
    }
    __syncthreads();

    // ---- GEMM 1 (W1 from global regs) ----
    f32x4 acc[4][2];
#pragma unroll
    for (int i0 = 0; i0 < 4; ++i0)
#pragma unroll
        for (int c0 = 0; c0 < 2; ++c0) { f32x4 z = {0.f,0.f,0.f,0.f}; acc[i0][c0] = z; }
    gemm_regW(W1f, Xb, acc, rw, cw, l);

    // ---- transition: bias + relu + split/pack X2 in regs ----
    u32 px[4][2][2][2];  // [itl][cg][hl][dword]
    {
        const float* b1n = b1 + n * HH;
#pragma unroll
        for (int itl = 0; itl < 4; ++itl) {
            const int ibase = (rw*4 + itl)*16 + t*4;
            float hv[4], dv[4];
#pragma unroll
            for (int r = 0; r < 4; ++r) {
                const float pre = acc[itl][0][r] + b1n[ibase + r];
                const bool  on  = pre > 0.f;
                hv[r] = on ? pre : 0.f;
                dv[r] = on ? acc[itl][1][r] : 0.f;
            }
#pragma unroll
            for (int cg = 0; cg < 2; ++cg) {
                const float* vs = cg ? dv : hv;
                u32 a0,c0,a1,c1,a2,c2,a3,c3;
                split1(vs[0],a0,c0); split1(vs[1],a1,c1);
                split1(vs[2],a2,c2); split1(vs[3],a3,c3);
                px[itl][cg][0][0] = a0 | (a1 << 16);
                px[itl][cg][0][1] = a2 | (a3 << 16);
                px[itl][cg][1][0] = c0 | (c1 << 16);
                px[itl][cg][1][1] = c2 | (c3 << 16);
            }
        }
    }
    __syncthreads();   // all GEMM1 reads of X1 complete

    // ---- write X2 frags ----
    {
#pragma unroll
        for (int itl = 0; itl < 4; ++itl) {
            const int IT   = rw*4 + itl;
            const int lane = ((IT & 1)*2 + (t >> 1))*16 + (l & 15);
            const int off8 = (t & 1)*8;
            const int ksn  = IT >> 1;
#pragma unroll
            for (int cg = 0; cg < 2; ++cg) {
                const int fq = (cw + cg*4)*4 + ksn;
#pragma unroll
                for (int hl = 0; hl < 2; ++hl) {
                    uint2 vv; vv.x = px[itl][cg][hl][0]; vv.y = px[itl][cg][hl][1];
                    *(uint2*)(Xb + ((fq*2 + hl)*64 + lane)*16 + off8) = vv;
                }
            }
        }
    }
    __syncthreads();

    // ---- GEMM 2 (W2 from global regs) ----
    f32x4 acc2[4][2];
#pragma unroll
    for (int i0 = 0; i0 < 4; ++i0)
#pragma unroll
        for (int c0 = 0; c0 < 2; ++c0) { f32x4 z = {0.f,0.f,0.f,0.f}; acc2[i0][c0] = z; }
    gemm_regW(W2f, Xb, acc2, rw, cw, l);

    // ---- layer 3: bias+relu then reduce with w3 ----
    float sh = 0.f, sd = 0.f;
    {
        const float* b2n = b2 + n * HH;
        const float* w3n = w3 + n * HH;
#pragma unroll
        for (int itl = 0; itl < 4; ++itl) {
            const int ibase = (rw*4 + itl)*16 + t*4;
#pragma unroll
            for (int r = 0; r < 4; ++r) {
                const int   i   = ibase + r;
                const float pre = acc2[itl][0][r] + b2n[i];
                const bool  on  = pre > 0.f;
                const float hv  = on ? pre : 0.f;
                const float dv  = on ? acc2[itl][1][r] : 0.f;
                const float wv  = w3n[i];
                sh = fmaf(wv, hv, sh);
                sd = fmaf(wv, dv, sd);
            }
        }
    }
    sh += __shfl_xor(sh, 16); sh += __shfl_xor(sh, 32);
    sd += __shfl_xor(sd, 16); sd += __shfl_xor(sd, 32);
    __syncthreads();   // all GEMM2 X reads done -> reuse LDS as reduction buffer
    if (t == 0) {
        const int p = cw * 16 + (l & 15);
        red[rw * 64 + p]        = sh;
        red[128 + rw * 64 + p]  = sd;
    }
    __syncthreads();

    // ---- epilogue (64 threads): square + JVP + trig, write both halves ----
    if (tid < 64) {
        const float oo = b3[n] + red[tid] + red[64 + tid];
        const float d2 = red[128 + tid] + red[192 + tid];
        const float bb = oo * oo;
        const float db = 2.f * oo * d2;
        const float sa = sqrt_a[n];
        const float af = sa * sa;
        const int   NL = NN * LL;
        const int   k1 = tile * BP + tid;
        if (k1 < PH) {
            {
                const float al = alpha[k1];
                const float sn = sinf(al), cs = cosf(al);
                const int base = n * LL + k1;
                out[base]          = af * (cs - 1.f);
                out[NL + base]     = bb * sn;
                out[2 * NL + base] = -af * sn;
                out[3 * NL + base] = fmaf(bb, cs, db * sn);
            }
            if (k1 <= PH - 2) {
                const int   k2  = (LL - 1) - k1;
                const float al2 = alpha[k2];
                const float sn2 = sinf(al2), cs2 = cosf(al2);
                const int base2 = n * LL + k2;
                out[base2]          = af * (cs2 - 1.f);
                out[NL + base2]     = bb * sn2;
                out[2 * NL + base2] = -af * sn2;
                out[3 * NL + base2] = fmaf(bb, cs2, -db * sn2);
            }
        }
    }
}

// =================== fallback (round-4 kernel, used if ws too small) =========

__device__ __forceinline__ void stageW_fb(const float* __restrict__ wn, char* Wb, int tid) {
#pragma unroll
    for (int it = 0; it < 4; ++it) {
        const int s  = tid + it * 512;
        const int l  = s & 63;
        const int fq = s >> 6;
        const int ks = fq & 3, it7 = fq >> 2;
        const int i  = it7 * 16 + (l & 15);
        const int k0 = ks * 32 + (l >> 4) * 8;
        const float4* src = (const float4*)(wn + i * HH + k0);
        const float4 va = src[0], vb = src[1];
        const float v[8] = {va.x, va.y, va.z, va.w, vb.x, vb.y, vb.z, vb.w};
        u32 hd[4], ld_[4];
#pragma unroll
        for (int q = 0; q < 4; ++q) {
            u32 h0, l0, h1, l1;
            split1(v[2*q], h0, l0); split1(v[2*q+1], h1, l1);
            hd[q]  = h0 | (h1 << 16);
            ld_[q] = l0 | (l1 << 16);
        }
        *(uint4*)(Wb + (((fq*2)+0)*64 + l)*16) = make_uint4(hd[0], hd[1], hd[2], hd[3]);
        *(uint4*)(Wb + (((fq*2)+1)*64 + l)*16) = make_uint4(ld_[0], ld_[1], ld_[2], ld_[3]);
    }
}

__device__ __forceinline__ void gemm128_fb(const char* Wb, const char* Xb,
                                           f32x4 acc[4][2], int rw, int cw, int l) {
    const bf16x8* Wf = (const bf16x8*)Wb;
    const bf16x8* Xf = (const bf16x8*)Xb;
#pragma unroll
    for (int ks = 0; ks < 4; ++ks) {
        bf16x8 Bh[2], Bl[2];
#pragma unroll
        for (int cg = 0; cg < 2; ++cg) {
            const int ct = cw + cg * 4;
            Bh[cg] = Xf[((ct*4 + ks)*2 + 0)*64 + l];
            Bl[cg] = Xf[((ct*4 + ks)*2 + 1)*64 + l];
        }
#pragma unroll
        for (int itl = 0; itl < 4; ++itl) {
            const int IT = rw * 4 + itl;
            const bf16x8 Ah = Wf[((IT*4 + ks)*2 + 0)*64 + l];
            const bf16x8 Al = Wf[((IT*4 + ks)*2 + 1)*64 + l];
#pragma unroll
            for (int cg = 0; cg < 2; ++cg) {
                acc[itl][cg] = MF(Ah, Bh[cg], acc[itl][cg]);
                acc[itl][cg] = MF(Ah, Bl[cg], acc[itl][cg]);
                acc[itl][cg] = MF(Al, Bh[cg], acc[itl][cg]);
            }
        }
    }
}

__global__ __launch_bounds__(512, 2) void sofa_mfma_fb(
    const float* __restrict__ alpha,
    const float* __restrict__ w0, const float* __restrict__ w1,
    const float* __restrict__ w2, const float* __restrict__ w3,
    const float* __restrict__ b0, const float* __restrict__ b1,
    const float* __restrict__ b2, const float* __restrict__ b3,
    const float* __restrict__ sqrt_a,
    float* __restrict__ out)
{
    __shared__ char smem[131072];
    char* Wb = smem;
    char* Xb = smem + 65536;
    float* red = (float*)smem;

    const int tile = blockIdx.x, n = blockIdx.y;
    const int tid = threadIdx.x;
    const int l   = tid & 63;
    const int w   = tid >> 6;
    const int rw  = w & 1;
    const int cw  = w >> 1;
    const int t   = l >> 4;

    stageW_fb(w1 + n * HH * HH, Wb, tid);
    {
        const float* w0n = w0 + n * HH;
        const float* b0n = b0 + n * HH;
        const int c  = tid & 127;
        const int jb = tid >> 7;
        int p = tile * BP + (c & 63);
        if (p > 2048) p = 2048;
        const float a = alpha[p];
        const bool isdh = c >= 64;
        const int ct = c >> 4;
#pragma unroll
        for (int g8 = 0; g8 < 4; ++g8) {
            u32 hd[4], ld_[4];
#pragma unroll
            for (int q = 0; q < 4; ++q) {
                float vv[2];
#pragma unroll
                for (int e = 0; e < 2; ++e) {
                    const int j = jb * 32 + g8 * 8 + q * 2 + e;
                    const float wv  = w0n[j];
                    const float pre = fmaf(wv, a, b0n[j]);
                    const bool  on  = pre > 0.f;
                    vv[e] = isdh ? (on ? wv : 0.f) : (on ? pre : 0.f);
                }
                u32 h0, l0, h1, l1;
                split1(vv[0], h0, l0); split1(vv[1], h1, l1);
                hd[q]  = h0 | (h1 << 16);
                ld_[q] = l0 | (l1 << 16);
            }
            const int lane = g8 * 16 + (c & 15);
            const int fq   = ct * 4 + jb;
            *(uint4*)(Xb + ((fq*2 + 0)*64 + lane)*16) = make_uint4(hd[0], hd[1], hd[2], hd[3]);
            *(uint4*)(Xb + ((fq*2 + 1)*64 + lane)*16) = make_uint4(ld_[0], ld_[1], ld_[2], ld_[3]);
        }
    }
    __syncthreads();

    f32x4 acc[4][2];
#pragma unroll
    for (int i0 = 0; i0 < 4; ++i0)
#pragma unroll
        for (int c0 = 0; c0 < 2; ++c0) { f32x4 z = {0.f,0.f,0.f,0.f}; acc[i0][c0] = z; }
    gemm128_fb(Wb, Xb, acc, rw, cw, l);

    u32 px[4][2][2][2];
    {
        const float* b1n = b1 + n * HH;
#pragma unroll
        for (int itl = 0; itl < 4; ++itl) {
            const int ibase = (rw*4 + itl)*16 + t*4;
            float hv[4], dv[4];
#pragma unroll
            for (int r = 0; r < 4; ++r) {
                const float pre = acc[itl][0][r] + b1n[ibase + r];
                const bool  on  = pre > 0.f;
                hv[r] = on ? pre : 0.f;
                dv[r] = on ? acc[itl][1][r] : 0.f;
            }
#pragma unroll
            for (int cg = 0; cg < 2; ++cg) {
                const float* vs = cg ? dv : hv;
                u32 a0,c0,a1,c1,a2,c2,a3,c3;
                split1(vs[0],a0,c0); split1(vs[1],a1,c1);
                split1(vs[2],a2,c2); split1(vs[3],a3,c3);
                px[itl][cg][0][0] = a0 | (a1 << 16);
                px[itl][cg][0][1] = a2 | (a3 << 16);
                px[itl][cg][1][0] = c0 | (c1 << 16);
                px[itl][cg][1][1] = c2 | (c3 << 16);
            }
        }
    }
    __syncthreads();

    stageW_fb(w2 + n * HH * HH, Wb, tid);
    {
#pragma unroll
        for (int itl = 0; itl < 4; ++itl) {
            const int IT   = rw*4 + itl;
            const int lane = ((IT & 1)*2 + (t >> 1))*16 + (l & 15);
            const int off8 = (t & 1)*8;
            const int ksn  = IT >> 1;
#pragma unroll
            for (int cg = 0; cg < 2; ++cg) {
                const int fq = (cw + cg*4)*4 + ksn;
#pragma unroll
                for (int hl = 0; hl < 2; ++hl) {
                    uint2 vv; vv.x = px[itl][cg][hl][0]; vv.y = px[itl][cg][hl][1];
                    *(uint2*)(Xb + ((fq*2 + hl)*64 + lane)*16 + off8) = vv;
                }
            }
        }
    }
    __syncthreads();

    f32x4 acc2[4][2];
#pragma unroll
    for (int i0 = 0; i0 < 4; ++i0)
#pragma unroll
        for (int c0 = 0; c0 < 2; ++c0) { f32x4 z = {0.f,0.f,0.f,0.f}; acc2[i0][c0] = z; }
    gemm128_fb(Wb, Xb, acc2, rw, cw, l);

    float sh = 0.f, sd = 0.f;
    {
        const float* b2n = b2 + n * HH;
        const float* w3n = w3 + n * HH;
#pragma unroll
        for (int itl = 0; itl < 4; ++itl) {
            const int ibase = (rw*4 + itl)*16 + t*4;
#pragma unroll
            for (int r = 0; r < 4; ++r) {
                const int   i   = ibase + r;
                const float pre = acc2[itl][0][r] + b2n[i];
                const bool  on  = pre > 0.f;
                const float hv  = on ? pre : 0.f;
                const float dv  = on ? acc2[itl][1][r] : 0.f;
                const float wv  = w3n[i];
                sh = fmaf(wv, hv, sh);
                sd = fmaf(wv, dv, sd);
            }
        }
    }
    sh += __shfl_xor(sh, 16); sh += __shfl_xor(sh, 32);
    sd += __shfl_xor(sd, 16); sd += __shfl_xor(sd, 32);
    __syncthreads();
    if (t == 0) {
        const int p = cw * 16 + (l & 15);
        red[rw * 64 + p]        = sh;
        red[128 + rw * 64 + p]  = sd;
    }
    __syncthreads();

    if (tid < 64) {
        const float oo = b3[n] + red[tid] + red[64 + tid];
        const float d2 = red[128 + tid] + red[192 + tid];
        const float bb = oo * oo;
        const float db = 2.f * oo * d2;
        const float sa = sqrt_a[n];
        const float af = sa * sa;
        const int   NL = NN * LL;
        const int   k1 = tile * BP + tid;
        if (k1 < PH) {
            {
                const float al = alpha[k1];
                const float sn = sinf(al), cs = cosf(al);
                const int base = n * LL + k1;
                out[base]          = af * (cs - 1.f);
                out[NL + base]     = bb * sn;
                out[2 * NL + base] = -af * sn;
                out[3 * NL + base] = fmaf(bb, cs, db * sn);
            }
            if (k1 <= PH - 2) {
                const int   k2  = (LL - 1) - k1;
                const float al2 = alpha[k2];
                const float sn2 = sinf(al2), cs2 = cosf(al2);
                const int base2 = n * LL + k2;
                out[base2]          = af * (cs2 - 1.f);
                out[NL + base2]     = bb * sn2;
                out[2 * NL + base2] = -af * sn2;
                out[3 * NL + base2] = fmaf(bb, cs2, -db * sn2);
            }
        }
    }
}

extern "C" void kernel_launch(void* const* d_in, const int* in_sizes, int n_in,
                              void* d_out, int out_size, void* d_ws, size_t ws_size,
                              hipStream_t stream) {
    const float* alpha  = (const float*)d_in[0];
    const float* w0     = (const float*)d_in[1];
    const float* w1     = (const float*)d_in[2];
    const float* w2     = (const float*)d_in[3];
    const float* w3     = (const float*)d_in[4];
    const float* b0     = (const float*)d_in[5];
    const float* b1     = (const float*)d_in[6];
    const float* b2     = (const float*)d_in[7];
    const float* b3     = (const float*)d_in[8];
    const float* sqrt_a = (const float*)d_in[9];
    (void)in_sizes; (void)n_in; (void)out_size;

    dim3 grid(NTILE, NN);
    if (ws_size >= (size_t)WS_NEEDED) {
        uint4* ws = (uint4*)d_ws;
        presplit<<<256, 512, 0, stream>>>(w1, w2, ws);
        sofa_mfma2<<<grid, 512, 0, stream>>>(alpha, w0, w3, b0, b1, b2, b3,
                                             sqrt_a, ws, (float*)d_out);
    } else {
        sofa_mfma_fb<<<grid, 512, 0, stream>>>(alpha, w0, w1, w2, w3,
                                               b0, b1, b2, b3, sqrt_a,
                                               (float*)d_out);
    }
}